// Round 1
// baseline (830.843 us; speedup 1.0000x reference)
//
#include <hip/hip_runtime.h>

#define T_ 32
#define B_ 32
#define H_ 128
#define W_ 128
#define C_ 2
#define NP_ 256
#define FH_ 32
#define CF_ 64
#define CP_ 32
#define OUT_ 128
#define PHW_ 64

// d_out layout (floats): out(4096) | logits_seq(131072) | sr(2) | active(1) | route(256) | chan(64)
#define OFF_LOGITS 4096
#define OFF_SR     135168
#define OFF_ACTIVE 135170
#define OFF_ROUTE  135171
#define OFF_CHAN   135427

// ---------------- K1: patch scores + event count ----------------
__global__ void __launch_bounds__(256) k_scores(const float* __restrict__ x,
    float* __restrict__ scores, unsigned* __restrict__ active_count) {
  const int tb = blockIdx.x;           // t*B + b
  const int p  = threadIdx.x;          // patch 0..255
  const int py = p >> 4, px = p & 15;
  const float* img = x + (size_t)tb * (H_*W_*C_);
  float s = 0.f;
  unsigned cnt = 0;
#pragma unroll
  for (int pr = 0; pr < 8; ++pr) {
    const float* row = img + ((size_t)(py*8 + pr)*W_ + px*8)*C_;
#pragma unroll
    for (int i = 0; i < 16; i += 4) {
      const float4 vv = *reinterpret_cast<const float4*>(row + i);
      float a;
      a = fabsf(vv.x); if (a > 0.5f) { s += a; ++cnt; }
      a = fabsf(vv.y); if (a > 0.5f) { s += a; ++cnt; }
      a = fabsf(vv.z); if (a > 0.5f) { s += a; ++cnt; }
      a = fabsf(vv.w); if (a > 0.5f) { s += a; ++cnt; }
    }
  }
  scores[tb*NP_ + p] = s * (1.f/128.f);
  unsigned c64 = cnt;
#pragma unroll
  for (int off = 32; off > 0; off >>= 1) c64 += __shfl_down(c64, off);
  __shared__ unsigned wsum[4];
  if ((p & 63) == 0) wsum[p >> 6] = c64;
  __syncthreads();
  if (p == 0) atomicAdd(active_count, wsum[0] + wsum[1] + wsum[2] + wsum[3]);
}

// ---------------- K2: region gate + argmax -> window coords ----------------
__global__ void __launch_bounds__(256) k_route(const float* __restrict__ scores,
    int2* __restrict__ y0x0, unsigned* __restrict__ route_count) {
  const int tb = blockIdx.x;
  const int p  = threadIdx.x;
  __shared__ float s[NP_];
  s[p] = scores[tb*NP_ + p];
  __syncthreads();
  const float v = s[p];
  int cg = 0, eqb = 0;
  for (int q = 0; q < NP_; ++q) {
    cg  += (s[q] > v) ? 1 : 0;
    eqb += ((s[q] == v) && (q < p)) ? 1 : 0;
  }
  if (cg < 4) atomicAdd(&route_count[p], 1u);
  if (cg == 0 && eqb == 0) {           // exactly one thread: first argmax
    const int cy = (p >> 4)*8 + 4;
    const int cx = (p & 15)*8 + 4;
    int y0 = cy - 16; y0 = y0 < 0 ? 0 : (y0 > 96 ? 96 : y0);
    int x0 = cx - 16; x0 = x0 < 0 ? 0 : (x0 > 96 ? 96 : x0);
    y0x0[tb] = make_int2(y0, x0);
  }
}

// ---------------- K3: fovea conv -> saliency -> channel gate ----------------
__global__ void __launch_bounds__(256) k_changate(const float* __restrict__ x,
    const float* __restrict__ wf, const int2* __restrict__ y0x0,
    float* __restrict__ chan_gate, unsigned* __restrict__ chan_count) {
  const int tb  = blockIdx.x;
  const int tid = threadIdx.x;
  __shared__ float tile[34*34*2];      // zero-padded 32x32x2 window
  __shared__ float part[256];
  __shared__ float salv[64];
  for (int i = tid; i < 34*34*2; i += 256) tile[i] = 0.f;
  __syncthreads();
  const int2 yx = y0x0[tb];
  const float* img = x + (size_t)tb*(H_*W_*C_);
  {
    const int row = tid >> 3, chunk = tid & 7;
    const float* src = img + ((size_t)(yx.x + row)*W_ + (yx.y + chunk*4))*C_;
    float* dst = &tile[((row + 1)*34 + (chunk*4 + 1))*2];
#pragma unroll
    for (int i = 0; i < 4; ++i) {
      float2 xv = *reinterpret_cast<const float2*>(src + i*2);
      dst[i*2]   = (fabsf(xv.x) > 0.5f) ? xv.x : 0.f;
      dst[i*2+1] = (fabsf(xv.y) > 0.5f) ? xv.y : 0.f;
    }
  }
  __syncthreads();
  const int c = tid & 63, g = tid >> 6;
  float wreg[18];
#pragma unroll
  for (int k = 0; k < 18; ++k) wreg[k] = wf[k*CF_ + c];
  float sal = 0.f;
  for (int yy = g*8; yy < g*8 + 8; ++yy) {
    for (int xx = 0; xx < 32; ++xx) {
      float acc = 0.f;
#pragma unroll
      for (int dy = 0; dy < 3; ++dy)
#pragma unroll
        for (int dx = 0; dx < 3; ++dx) {
          const int ti = ((yy + dy)*34 + xx + dx)*2;
          acc += tile[ti]*wreg[(dy*3+dx)*2] + tile[ti+1]*wreg[(dy*3+dx)*2+1];
        }
      sal += fabsf(acc);
    }
  }
  part[tid] = sal;
  __syncthreads();
  if (tid < 64)
    salv[tid] = (part[tid] + part[64+tid] + part[128+tid] + part[192+tid]) * (1.f/1024.f);
  __syncthreads();
  if (tid < 64) {
    const float sv = salv[tid];
    int cg = 0;
    for (int q = 0; q < 64; ++q) cg += (salv[q] > sv) ? 1 : 0;
    const float gate = (cg < 16) ? 1.f : 0.f;
    chan_gate[tb*CF_ + tid] = gate;
    if (gate > 0.f) atomicAdd(&chan_count[tid], 1u);
  }
}

// ---------------- K4: persistent fovea membrane ----------------
__global__ void __launch_bounds__(256) k_fovea(const float* __restrict__ x,
    const float* __restrict__ wf, const int2* __restrict__ y0x0,
    const float* __restrict__ chan_gate, unsigned* __restrict__ sf_cnt) {
  const int blk = blockIdx.x;          // b*8 + stripe
  const int b = blk >> 3, stripe = blk & 7;
  const int tid = threadIdx.x;
  const int c = tid & 63, sub = tid >> 6;   // row within 4-row stripe
  __shared__ float tile[6*34*2];
  __shared__ unsigned redu[256];
  float wreg[18];
#pragma unroll
  for (int k = 0; k < 18; ++k) wreg[k] = wf[k*CF_ + c];
  float v[32];
#pragma unroll
  for (int i = 0; i < 32; ++i) v[i] = 0.f;
  for (int i = tid; i < 6*34*2; i += 256) tile[i] = 0.f;  // zero incl. col borders
  __syncthreads();
  for (int t = 0; t < T_; ++t) {
    const int tb = t*B_ + b;
    const int2 yx = y0x0[tb];
    const float gate = chan_gate[tb*CF_ + c];
    if (tid < 192) {                   // stage 6 rows x 32 cols x 2ch
      const int row6 = tid >> 5, col = tid & 31;
      const int wr = stripe*4 - 1 + row6;
      float v0 = 0.f, v1 = 0.f;
      if (wr >= 0 && wr < FH_) {
        const float2 xv = *reinterpret_cast<const float2*>(
            x + (size_t)tb*(H_*W_*C_) + ((size_t)(yx.x + wr)*W_ + (yx.y + col))*C_);
        v0 = (fabsf(xv.x) > 0.5f) ? xv.x : 0.f;
        v1 = (fabsf(xv.y) > 0.5f) ? xv.y : 0.f;
      }
      tile[(row6*34 + col + 1)*2]     = v0;
      tile[(row6*34 + col + 1)*2 + 1] = v1;
    }
    __syncthreads();
    unsigned cnt = 0;
#pragma unroll
    for (int xx = 0; xx < 32; ++xx) {
      float acc = 0.f;
#pragma unroll
      for (int dy = 0; dy < 3; ++dy)
#pragma unroll
        for (int dx = 0; dx < 3; ++dx) {
          const int ti = ((sub + dy)*34 + xx + dx)*2;
          acc += tile[ti]*wreg[(dy*3+dx)*2] + tile[ti+1]*wreg[(dy*3+dx)*2+1];
        }
      float nv = 0.9f*v[xx] + acc*gate;
      if (nv > 1.0f) { nv -= 1.0f; ++cnt; }
      v[xx] = nv;
    }
    redu[tid] = cnt;                   // layout [sub][c]
    __syncthreads();
    if (sub == 0) {
      const unsigned ssum = redu[c] + redu[64 + c] + redu[128 + c] + redu[192 + c];
      atomicAdd(&sf_cnt[tb*CF_ + c], ssum);
    }
    __syncthreads();
  }
}

// ---------------- K5: persistent periph membrane ----------------
__global__ void __launch_bounds__(256) k_periph(const float* __restrict__ x,
    const float* __restrict__ wp, unsigned* __restrict__ sp_cnt) {
  const int blk = blockIdx.x;          // b*16 + stripe
  const int b = blk >> 4, stripe = blk & 15;
  const int r0 = stripe*4;             // first periph row of stripe
  const int tid = threadIdx.x;
  const int c = tid & 31, g = tid >> 5;
  const int prow = g >> 1, pcol0 = (g & 1)*32;
  __shared__ float xt[14*W_*C_];       // raw image rows 2r0-3 .. 2r0+10 (masked)
  __shared__ float pt[6*66*2];         // periph rows r0-1..r0+4, cols -1..64
  __shared__ unsigned redu[256];
  float wreg[18];
#pragma unroll
  for (int k = 0; k < 18; ++k) wreg[k] = wp[k*CP_ + c];
  float v[32];
#pragma unroll
  for (int i = 0; i < 32; ++i) v[i] = 0.f;
  for (int t = 0; t < T_; ++t) {
    const int tb = t*B_ + b;
    const float* img = x + (size_t)tb*(H_*W_*C_);
#pragma unroll
    for (int r = 0; r < 14; ++r) {
      const int xr = 2*r0 - 3 + r;
      float val = 0.f;
      if (xr >= 0 && xr < H_) {
        val = img[(size_t)xr*(W_*C_) + tid];
        if (!(fabsf(val) > 0.5f)) val = 0.f;
      }
      xt[r*(W_*C_) + tid] = val;
    }
    __syncthreads();
    // build antialiased bilinear-downsample tile (jax.image.resize 'linear')
    for (int idx = tid; idx < 6*66*2; idx += 256) {
      const int ci = idx & 1;
      const int rest = idx >> 1;
      const int row6 = rest / 66, col66 = rest % 66;
      const int pr = r0 - 1 + row6, ps = col66 - 1;
      float val = 0.f;
      if (pr >= 0 && pr < PHW_ && ps >= 0 && ps < PHW_) {
        float wy[4] = {0.125f, 0.375f, 0.375f, 0.125f};
        if (pr == 0)        { wy[0]=0.f;      wy[1]=3.f/7.f; wy[2]=3.f/7.f; wy[3]=1.f/7.f; }
        else if (pr == 63)  { wy[0]=1.f/7.f;  wy[1]=3.f/7.f; wy[2]=3.f/7.f; wy[3]=0.f; }
        float wx[4] = {0.125f, 0.375f, 0.375f, 0.125f};
        if (ps == 0)        { wx[0]=0.f;      wx[1]=3.f/7.f; wx[2]=3.f/7.f; wx[3]=1.f/7.f; }
        else if (ps == 63)  { wx[0]=1.f/7.f;  wx[1]=3.f/7.f; wx[2]=3.f/7.f; wx[3]=0.f; }
        const int lr0 = 2*row6;          // local xt row of tap j=0
        const int cc0 = 2*ps - 1;
#pragma unroll
        for (int j = 0; j < 4; ++j) {
          float h = 0.f;
#pragma unroll
          for (int i = 0; i < 4; ++i) {
            int cc = cc0 + i; cc = cc < 0 ? 0 : (cc > W_-1 ? W_-1 : cc);  // w=0 at borders anyway
            h += wx[i]*xt[((lr0 + j)*W_ + cc)*C_ + ci];
          }
          val += wy[j]*h;
        }
      }
      pt[idx] = val;
    }
    __syncthreads();
    unsigned cnt = 0;
#pragma unroll
    for (int xx = 0; xx < 32; ++xx) {
      float acc = 0.f;
      const int pc = pcol0 + xx;
#pragma unroll
      for (int dy = 0; dy < 3; ++dy)
#pragma unroll
        for (int dx = 0; dx < 3; ++dx) {
          const int ti = ((prow + dy)*66 + pc + dx)*2;
          acc += pt[ti]*wreg[(dy*3+dx)*2] + pt[ti+1]*wreg[(dy*3+dx)*2+1];
        }
      float nv = 0.9f*v[xx] + acc;
      if (nv > 1.0f) { nv -= 1.0f; ++cnt; }
      v[xx] = nv;
    }
    redu[tid] = cnt;
    __syncthreads();
    if (g == 0) {
      unsigned ssum = 0;
#pragma unroll
      for (int j = 0; j < 8; ++j) ssum += redu[j*32 + c];
      atomicAdd(&sp_cnt[tb*CP_ + c], ssum);
    }
    __syncthreads();
  }
}

// ---------------- K6: logits ----------------
__global__ void __launch_bounds__(128) k_logits(const float* __restrict__ scores,
    const unsigned* __restrict__ sf_cnt, const unsigned* __restrict__ sp_cnt,
    const float* __restrict__ head_w, const float* __restrict__ head_b,
    const float* __restrict__ route_w, const float* __restrict__ route_b,
    float* __restrict__ logits) {
  const int tb = blockIdx.x, o = threadIdx.x;
  __shared__ float sc[NP_];
  __shared__ float fu[96];
  sc[o]       = scores[tb*NP_ + o];
  sc[o + 128] = scores[tb*NP_ + o + 128];
  if (o < 64)       fu[o] = (float)sf_cnt[tb*CF_ + o] * (1.f/1024.f);
  else if (o < 96)  fu[o] = (float)sp_cnt[tb*CP_ + (o - 64)] * (1.f/4096.f);
  __syncthreads();
  float acc = head_b[o] + route_b[o];
#pragma unroll 8
  for (int k = 0; k < 96; ++k)  acc += fu[k]*head_w[k*OUT_ + o];
#pragma unroll 8
  for (int p = 0; p < NP_; ++p) acc += sc[p]*route_w[p*OUT_ + o];
  logits[tb*OUT_ + o] = acc;
}

// ---------------- K7: finalize ----------------
__global__ void __launch_bounds__(256) k_final(const float* __restrict__ logits,
    float* __restrict__ dout, const unsigned* __restrict__ sf_cnt,
    const unsigned* __restrict__ sp_cnt, const unsigned* __restrict__ cnts) {
  const int blk = blockIdx.x, tid = threadIdx.x;
  if (blk < 16) {
    const int idx = blk*256 + tid;     // 0..4095
    const int b = idx >> 7, o = idx & 127;
    float s = 0.f;
#pragma unroll
    for (int t = 0; t < T_; ++t) s += logits[(t*B_ + b)*OUT_ + o];
    dout[idx] = s * (1.f/32.f);
  } else {
    unsigned sfs = 0, sps = 0;
    for (int i = tid; i < T_*B_*CF_; i += 256) sfs += sf_cnt[i];
    for (int i = tid; i < T_*B_*CP_; i += 256) sps += sp_cnt[i];
    __shared__ unsigned r1[256], r2[256];
    r1[tid] = sfs; r2[tid] = sps;
    __syncthreads();
    for (int off = 128; off > 0; off >>= 1) {
      if (tid < off) { r1[tid] += r1[tid + off]; r2[tid] += r2[tid + off]; }
      __syncthreads();
    }
    if (tid == 0) {
      dout[OFF_SR]     = (float)r1[0] * (1.f/67108864.f);    // T*B*32*32*64
      dout[OFF_SR + 1] = (float)r2[0] * (1.f/134217728.f);   // T*B*64*64*32
      dout[OFF_ACTIVE] = (float)cnts[0] * (1.f/33554432.f);  // T*B*H*W*C
    }
    dout[OFF_ROUTE + tid] = (float)cnts[1 + tid] * (1.f/1024.f);
    if (tid < 64) dout[OFF_CHAN + tid] = (float)cnts[257 + tid] * (1.f/1024.f);
  }
}

extern "C" void kernel_launch(void* const* d_in, const int* in_sizes, int n_in,
                              void* d_out, int out_size, void* d_ws, size_t ws_size,
                              hipStream_t stream) {
  const float* x       = (const float*)d_in[0];
  const float* wf      = (const float*)d_in[1];
  const float* wp      = (const float*)d_in[2];
  const float* head_w  = (const float*)d_in[3];
  const float* head_b  = (const float*)d_in[4];
  const float* route_w = (const float*)d_in[5];
  const float* route_b = (const float*)d_in[6];
  float* out = (float*)d_out;

  float*    ws_scores = (float*)d_ws;                    // T*B*256
  float*    ws_gate   = ws_scores + T_*B_*NP_;           // T*B*64
  int2*     ws_yx     = (int2*)(ws_gate + T_*B_*CF_);    // T*B
  unsigned* ws_sf     = (unsigned*)(ws_yx + T_*B_);      // T*B*64
  unsigned* ws_sp     = ws_sf + T_*B_*CF_;               // T*B*32
  unsigned* ws_cnt    = ws_sp + T_*B_*CP_;               // 1 + 256 + 64

  hipMemsetAsync(ws_sf, 0, (size_t)(T_*B_*CF_ + T_*B_*CP_ + 321)*sizeof(unsigned), stream);

  k_scores  <<<T_*B_, 256, 0, stream>>>(x, ws_scores, ws_cnt);
  k_route   <<<T_*B_, 256, 0, stream>>>(ws_scores, ws_yx, ws_cnt + 1);
  k_changate<<<T_*B_, 256, 0, stream>>>(x, wf, ws_yx, ws_gate, ws_cnt + 257);
  k_fovea   <<<B_*8,  256, 0, stream>>>(x, wf, ws_yx, ws_gate, ws_sf);
  k_periph  <<<B_*16, 256, 0, stream>>>(x, wp, ws_sp);
  k_logits  <<<T_*B_, 128, 0, stream>>>(ws_scores, ws_sf, ws_sp, head_w, head_b,
                                        route_w, route_b, out + OFF_LOGITS);
  k_final   <<<17, 256, 0, stream>>>(out + OFF_LOGITS, out, ws_sf, ws_sp, ws_cnt);
}

// Round 2
// 535.326 us; speedup vs baseline: 1.5520x; 1.5520x over previous
//
#include <hip/hip_runtime.h>

#define T_ 32
#define B_ 32
#define H_ 128
#define W_ 128
#define C_ 2
#define NP_ 256
#define FH_ 32
#define CF_ 64
#define CP_ 32
#define OUT_ 128
#define PHW_ 64

// d_out layout (floats): out(4096) | logits_seq(131072) | sr(2) | active(1) | route(256) | chan(64)
#define OFF_LOGITS 4096
#define OFF_SR     135168
#define OFF_ACTIVE 135170
#define OFF_ROUTE  135171
#define OFF_CHAN   135427

// ---------------- K1: patch scores + event count + region gate + argmax ----------------
__global__ void __launch_bounds__(256) k_scores(const float* __restrict__ x,
    float* __restrict__ scores, unsigned* __restrict__ active_count,
    int2* __restrict__ y0x0, unsigned* __restrict__ route_count) {
  const int tb = blockIdx.x;           // t*B + b
  const int p  = threadIdx.x;          // patch 0..255
  const int py = p >> 4, px = p & 15;
  const float* img = x + (size_t)tb * (H_*W_*C_);
  float s = 0.f;
  unsigned cnt = 0;
#pragma unroll
  for (int pr = 0; pr < 8; ++pr) {
    const float* row = img + ((size_t)(py*8 + pr)*W_ + px*8)*C_;
#pragma unroll
    for (int i = 0; i < 16; i += 4) {
      const float4 vv = *reinterpret_cast<const float4*>(row + i);
      float a;
      a = fabsf(vv.x); if (a > 0.5f) { s += a; ++cnt; }
      a = fabsf(vv.y); if (a > 0.5f) { s += a; ++cnt; }
      a = fabsf(vv.z); if (a > 0.5f) { s += a; ++cnt; }
      a = fabsf(vv.w); if (a > 0.5f) { s += a; ++cnt; }
    }
  }
  __shared__ float sm[NP_];
  const float sv = s * (1.f/128.f);
  sm[p] = sv;
  scores[tb*NP_ + p] = sv;
  unsigned c64 = cnt;
#pragma unroll
  for (int off = 32; off > 0; off >>= 1) c64 += __shfl_down(c64, off);
  __shared__ unsigned wsum[4];
  if ((p & 63) == 0) wsum[p >> 6] = c64;
  __syncthreads();
  if (p == 0) atomicAdd(active_count, wsum[0] + wsum[1] + wsum[2] + wsum[3]);
  // region gate + first-index argmax
  int cg = 0, eqb = 0;
  for (int q = 0; q < NP_; ++q) {
    cg  += (sm[q] > sv) ? 1 : 0;
    eqb += ((sm[q] == sv) && (q < p)) ? 1 : 0;
  }
  if (cg < 4) atomicAdd(&route_count[p], 1u);
  if (cg == 0 && eqb == 0) {
    const int cy = py*8 + 4, cx = px*8 + 4;
    int y0 = cy - 16; y0 = y0 < 0 ? 0 : (y0 > 96 ? 96 : y0);
    int x0 = cx - 16; x0 = x0 < 0 ? 0 : (x0 > 96 ? 96 : x0);
    y0x0[tb] = make_int2(y0, x0);
  }
}

// ---------------- K2: masked antialiased 2x downsample -> P[T][B][64][64][2] ----------------
__global__ void __launch_bounds__(256) k_down(const float* __restrict__ x,
    float* __restrict__ P) {
  const int blk = blockIdx.x;          // tb*4 + chunk
  const int tb = blk >> 2, chunk = blk & 3;
  const int r0 = chunk*16;             // periph rows r0..r0+15
  const int tid = threadIdx.x;
  __shared__ float xt[34*256];         // raw rows 2r0-1 .. 2r0+32, masked
  const float* img = x + (size_t)tb*(H_*W_*C_);
  for (int i = tid; i < 34*256; i += 256) {
    const int rr = i >> 8, off = i & 255;
    const int xr = 2*r0 - 1 + rr;
    float val = 0.f;
    if (xr >= 0 && xr < H_) {
      val = img[(size_t)xr*256 + off];
      if (!(fabsf(val) > 0.5f)) val = 0.f;
    }
    xt[i] = val;
  }
  __syncthreads();
#pragma unroll
  for (int k = 0; k < 8; ++k) {
    const int idx = k*256 + tid;       // 0..2047 = (row16*64+col)*2+ci
    const int ci = idx & 1, rest = idx >> 1;
    const int col = rest & 63, row16 = rest >> 6;
    const int pr = r0 + row16;
    float wy[4] = {0.125f, 0.375f, 0.375f, 0.125f};
    if (pr == 0)        { wy[0]=0.f;     wy[1]=3.f/7.f; wy[2]=3.f/7.f; wy[3]=1.f/7.f; }
    else if (pr == 63)  { wy[0]=1.f/7.f; wy[1]=3.f/7.f; wy[2]=3.f/7.f; wy[3]=0.f; }
    float wx[4] = {0.125f, 0.375f, 0.375f, 0.125f};
    if (col == 0)       { wx[0]=0.f;     wx[1]=3.f/7.f; wx[2]=3.f/7.f; wx[3]=1.f/7.f; }
    else if (col == 63) { wx[0]=1.f/7.f; wx[1]=3.f/7.f; wx[2]=3.f/7.f; wx[3]=0.f; }
    const int lr = 2*row16;            // xt row of tap j=0 (raw row 2pr-1)
    const int cc0 = 2*col - 1;
    float val = 0.f;
#pragma unroll
    for (int j = 0; j < 4; ++j) {
      float h = 0.f;
#pragma unroll
      for (int i = 0; i < 4; ++i) {
        int cc = cc0 + i; cc = cc < 0 ? 0 : (cc > W_-1 ? W_-1 : cc);
        h += wx[i]*xt[(lr + j)*256 + cc*2 + ci];
      }
      val += wy[j]*h;
    }
    P[(size_t)tb*8192 + pr*128 + col*2 + ci] = val;
  }
}

// ---------------- K3: fovea conv -> saliency -> channel gate ----------------
__global__ void __launch_bounds__(256) k_changate(const float* __restrict__ x,
    const float* __restrict__ wf, const int2* __restrict__ y0x0,
    float* __restrict__ chan_gate, unsigned* __restrict__ chan_count) {
  const int tb  = blockIdx.x;
  const int tid = threadIdx.x;
  __shared__ float tile[34*34*2];      // zero-padded 32x32x2 window
  __shared__ float part[256];
  __shared__ float salv[64];
  for (int i = tid; i < 34*34*2; i += 256) tile[i] = 0.f;
  __syncthreads();
  const int2 yx = y0x0[tb];
  const float* img = x + (size_t)tb*(H_*W_*C_);
  {
    const int row = tid >> 3, chunk = tid & 7;
    const float* src = img + ((size_t)(yx.x + row)*W_ + (yx.y + chunk*4))*C_;
    float* dst = &tile[((row + 1)*34 + (chunk*4 + 1))*2];
#pragma unroll
    for (int i = 0; i < 4; ++i) {
      float2 xv = *reinterpret_cast<const float2*>(src + i*2);
      dst[i*2]   = (fabsf(xv.x) > 0.5f) ? xv.x : 0.f;
      dst[i*2+1] = (fabsf(xv.y) > 0.5f) ? xv.y : 0.f;
    }
  }
  __syncthreads();
  const int c = tid & 63, g = tid >> 6;
  float wreg[18];
#pragma unroll
  for (int k = 0; k < 18; ++k) wreg[k] = wf[k*CF_ + c];
  float sal = 0.f;
  for (int yy = g*8; yy < g*8 + 8; ++yy) {
    for (int xx = 0; xx < 32; ++xx) {
      float acc = 0.f;
#pragma unroll
      for (int dy = 0; dy < 3; ++dy)
#pragma unroll
        for (int dx = 0; dx < 3; ++dx) {
          const int ti = ((yy + dy)*34 + xx + dx)*2;
          acc += tile[ti]*wreg[(dy*3+dx)*2] + tile[ti+1]*wreg[(dy*3+dx)*2+1];
        }
      sal += fabsf(acc);
    }
  }
  part[tid] = sal;
  __syncthreads();
  if (tid < 64)
    salv[tid] = (part[tid] + part[64+tid] + part[128+tid] + part[192+tid]) * (1.f/1024.f);
  __syncthreads();
  if (tid < 64) {
    const float sv = salv[tid];
    int cg = 0;
    for (int q = 0; q < 64; ++q) cg += (salv[q] > sv) ? 1 : 0;
    const float gate = (cg < 16) ? 1.f : 0.f;
    chan_gate[tb*CF_ + tid] = gate;
    if (gate > 0.f) atomicAdd(&chan_count[tid], 1u);
  }
}

// ---------------- K4: persistent fovea membrane (1 block per (b,row)) ----------------
__global__ void __launch_bounds__(256) k_fovea(const float* __restrict__ x,
    const float* __restrict__ wf, const int2* __restrict__ y0x0,
    const float* __restrict__ chan_gate, unsigned* __restrict__ sf_cnt) {
  const int blk = blockIdx.x;          // b*32 + row
  const int b = blk >> 5, row = blk & 31;
  const int tid = threadIdx.x;
  const int c = tid & 63, xg = tid >> 6;    // channel, x-group (8 px each)
  __shared__ float tile[3*34*2];       // window rows row-1..row+1, cols -1..32
  __shared__ unsigned redu[256];
  float wreg[18];
#pragma unroll
  for (int k = 0; k < 18; ++k) wreg[k] = wf[k*CF_ + c];
  float v[8];
#pragma unroll
  for (int i = 0; i < 8; ++i) v[i] = 0.f;
  if (tid < 12) {                      // zero col-pad (cols -1 and 32), 3 rows x 2 ch
    const int r3 = tid / 4, rem = tid & 3;
    tile[(r3*34 + (rem >> 1)*33)*2 + (rem & 1)] = 0.f;
  }
  for (int t = 0; t < T_; ++t) {
    const int tb = t*B_ + b;
    const int2 yx = y0x0[tb];
    const float gate = chan_gate[tb*CF_ + c];
    if (tid < 192) {                   // 3 rows x 32 cols x 2 ch
      const int rr = tid >> 6, off = tid & 63;
      const int wr = row - 1 + rr;
      float val = 0.f;
      if (wr >= 0 && wr < FH_) {
        val = x[(size_t)tb*(H_*W_*C_) + ((size_t)(yx.x + wr)*W_ + yx.y)*C_ + off];
        if (!(fabsf(val) > 0.5f)) val = 0.f;
      }
      tile[(rr*34 + 1)*2 + off] = val;
    }
    __syncthreads();
    unsigned cnt = 0;
#pragma unroll
    for (int k = 0; k < 8; ++k) {
      const int xx = xg*8 + k;
      float acc = 0.f;
#pragma unroll
      for (int dy = 0; dy < 3; ++dy)
#pragma unroll
        for (int dx = 0; dx < 3; ++dx) {
          const int ti = (dy*34 + xx + dx)*2;
          acc += tile[ti]*wreg[(dy*3+dx)*2] + tile[ti+1]*wreg[(dy*3+dx)*2+1];
        }
      float nv = 0.9f*v[k] + acc*gate;
      if (nv > 1.0f) { nv -= 1.0f; ++cnt; }
      v[k] = nv;
    }
    redu[tid] = cnt;                   // [xg][c]
    __syncthreads();
    if (tid < 64)
      atomicAdd(&sf_cnt[tb*CF_ + tid],
                redu[tid] + redu[64 + tid] + redu[128 + tid] + redu[192 + tid]);
  }
}

// ---------------- K5: persistent periph membrane (1 block per (b,row)) ----------------
__global__ void __launch_bounds__(256) k_periph(const float* __restrict__ P,
    const float* __restrict__ wp, unsigned* __restrict__ sp_cnt) {
  const int blk = blockIdx.x;          // b*64 + row
  const int b = blk >> 6, row = blk & 63;
  const int tid = threadIdx.x;
  const int c = tid & 31, xg = tid >> 5;    // channel, x-group (8 px each)
  __shared__ float pt[3*66*2];         // periph rows row-1..row+1, cols -1..64
  __shared__ unsigned redu[256];
  float wreg[18];
#pragma unroll
  for (int k = 0; k < 18; ++k) wreg[k] = wp[k*CP_ + c];
  float v[8];
#pragma unroll
  for (int i = 0; i < 8; ++i) v[i] = 0.f;
  if (tid < 12) {                      // zero col-pad (cols -1 and 64)
    const int r3 = tid / 4, rem = tid & 3;
    pt[(r3*66 + (rem >> 1)*65)*2 + (rem & 1)] = 0.f;
  }
  for (int t = 0; t < T_; ++t) {
    const int tb = t*B_ + b;
    for (int i = tid; i < 384; i += 256) {   // 3 rows x 128 floats
      const int rr = i >> 7, off = i & 127;
      const int pr = row - 1 + rr;
      float val = 0.f;
      if (pr >= 0 && pr < PHW_) val = P[(size_t)tb*8192 + pr*128 + off];
      pt[(rr*66 + 1)*2 + off] = val;
    }
    __syncthreads();
    unsigned cnt = 0;
#pragma unroll
    for (int k = 0; k < 8; ++k) {
      const int xx = xg*8 + k;
      float acc = 0.f;
#pragma unroll
      for (int dy = 0; dy < 3; ++dy)
#pragma unroll
        for (int dx = 0; dx < 3; ++dx) {
          const int ti = (dy*66 + xx + dx)*2;
          acc += pt[ti]*wreg[(dy*3+dx)*2] + pt[ti+1]*wreg[(dy*3+dx)*2+1];
        }
      float nv = 0.9f*v[k] + acc;
      if (nv > 1.0f) { nv -= 1.0f; ++cnt; }
      v[k] = nv;
    }
    redu[tid] = cnt;                   // [xg][c]
    __syncthreads();
    if (tid < 32) {
      unsigned ssum = 0;
#pragma unroll
      for (int j = 0; j < 8; ++j) ssum += redu[j*32 + tid];
      atomicAdd(&sp_cnt[tb*CP_ + tid], ssum);
    }
    __syncthreads();
  }
}

// ---------------- K6: logits ----------------
__global__ void __launch_bounds__(128) k_logits(const float* __restrict__ scores,
    const unsigned* __restrict__ sf_cnt, const unsigned* __restrict__ sp_cnt,
    const float* __restrict__ head_w, const float* __restrict__ head_b,
    const float* __restrict__ route_w, const float* __restrict__ route_b,
    float* __restrict__ logits) {
  const int tb = blockIdx.x, o = threadIdx.x;
  __shared__ float sc[NP_];
  __shared__ float fu[96];
  sc[o]       = scores[tb*NP_ + o];
  sc[o + 128] = scores[tb*NP_ + o + 128];
  if (o < 64)       fu[o] = (float)sf_cnt[tb*CF_ + o] * (1.f/1024.f);
  else if (o < 96)  fu[o] = (float)sp_cnt[tb*CP_ + (o - 64)] * (1.f/4096.f);
  __syncthreads();
  float acc = head_b[o] + route_b[o];
#pragma unroll 8
  for (int k = 0; k < 96; ++k)  acc += fu[k]*head_w[k*OUT_ + o];
#pragma unroll 8
  for (int p = 0; p < NP_; ++p) acc += sc[p]*route_w[p*OUT_ + o];
  logits[tb*OUT_ + o] = acc;
}

// ---------------- K7: finalize ----------------
__global__ void __launch_bounds__(256) k_final(const float* __restrict__ logits,
    float* __restrict__ dout, const unsigned* __restrict__ sf_cnt,
    const unsigned* __restrict__ sp_cnt, const unsigned* __restrict__ cnts) {
  const int blk = blockIdx.x, tid = threadIdx.x;
  if (blk < 16) {
    const int idx = blk*256 + tid;     // 0..4095
    const int b = idx >> 7, o = idx & 127;
    float s = 0.f;
#pragma unroll
    for (int t = 0; t < T_; ++t) s += logits[(t*B_ + b)*OUT_ + o];
    dout[idx] = s * (1.f/32.f);
  } else {
    unsigned sfs = 0, sps = 0;
    for (int i = tid; i < T_*B_*CF_; i += 256) sfs += sf_cnt[i];
    for (int i = tid; i < T_*B_*CP_; i += 256) sps += sp_cnt[i];
    __shared__ unsigned r1[256], r2[256];
    r1[tid] = sfs; r2[tid] = sps;
    __syncthreads();
    for (int off = 128; off > 0; off >>= 1) {
      if (tid < off) { r1[tid] += r1[tid + off]; r2[tid] += r2[tid + off]; }
      __syncthreads();
    }
    if (tid == 0) {
      dout[OFF_SR]     = (float)r1[0] * (1.f/67108864.f);    // T*B*32*32*64
      dout[OFF_SR + 1] = (float)r2[0] * (1.f/134217728.f);   // T*B*64*64*32
      dout[OFF_ACTIVE] = (float)cnts[0] * (1.f/33554432.f);  // T*B*H*W*C
    }
    dout[OFF_ROUTE + tid] = (float)cnts[1 + tid] * (1.f/1024.f);
    if (tid < 64) dout[OFF_CHAN + tid] = (float)cnts[257 + tid] * (1.f/1024.f);
  }
}

extern "C" void kernel_launch(void* const* d_in, const int* in_sizes, int n_in,
                              void* d_out, int out_size, void* d_ws, size_t ws_size,
                              hipStream_t stream) {
  const float* x       = (const float*)d_in[0];
  const float* wf      = (const float*)d_in[1];
  const float* wp      = (const float*)d_in[2];
  const float* head_w  = (const float*)d_in[3];
  const float* head_b  = (const float*)d_in[4];
  const float* route_w = (const float*)d_in[5];
  const float* route_b = (const float*)d_in[6];
  float* out = (float*)d_out;

  float*    ws_P      = (float*)d_ws;                    // T*B*64*64*2 = 8.4M floats
  float*    ws_scores = ws_P + (size_t)T_*B_*8192;       // T*B*256
  float*    ws_gate   = ws_scores + T_*B_*NP_;           // T*B*64
  int2*     ws_yx     = (int2*)(ws_gate + T_*B_*CF_);    // T*B
  unsigned* ws_sf     = (unsigned*)(ws_yx + T_*B_);      // T*B*64
  unsigned* ws_sp     = ws_sf + T_*B_*CF_;               // T*B*32
  unsigned* ws_cnt    = ws_sp + T_*B_*CP_;               // 1 + 256 + 64

  hipMemsetAsync(ws_sf, 0, (size_t)(T_*B_*CF_ + T_*B_*CP_ + 321)*sizeof(unsigned), stream);

  k_scores  <<<T_*B_,   256, 0, stream>>>(x, ws_scores, ws_cnt, ws_yx, ws_cnt + 1);
  k_down    <<<T_*B_*4, 256, 0, stream>>>(x, ws_P);
  k_changate<<<T_*B_,   256, 0, stream>>>(x, wf, ws_yx, ws_gate, ws_cnt + 257);
  k_fovea   <<<B_*32,   256, 0, stream>>>(x, wf, ws_yx, ws_gate, ws_sf);
  k_periph  <<<B_*64,   256, 0, stream>>>(ws_P, wp, ws_sp);
  k_logits  <<<T_*B_,   128, 0, stream>>>(ws_scores, ws_sf, ws_sp, head_w, head_b,
                                          route_w, route_b, out + OFF_LOGITS);
  k_final   <<<17, 256, 0, stream>>>(out + OFF_LOGITS, out, ws_sf, ws_sp, ws_cnt);
}

// Round 3
// 491.378 us; speedup vs baseline: 1.6908x; 1.0894x over previous
//
#include <hip/hip_runtime.h>

#define T_ 32
#define B_ 32
#define H_ 128
#define W_ 128
#define C_ 2
#define NP_ 256
#define CF_ 64
#define CP_ 32
#define OUT_ 128

// padded periph image: rows -1..64 (66), px -2..65 (68) * 2ch = 136 floats/row
#define PROW 136
#define PTB  8976    // 66*136 floats per (t,b)

// d_out layout (floats): out(4096) | logits_seq(131072) | sr(2) | active(1) | route(256) | chan(64)
#define OFF_LOGITS 4096
#define OFF_SR     135168
#define OFF_ACTIVE 135170
#define OFF_ROUTE  135171
#define OFF_CHAN   135427

__device__ __forceinline__ float f4c(const float4& v, int i) {
  switch (i & 3) { case 0: return v.x; case 1: return v.y; case 2: return v.z; default: return v.w; }
}

// ---------------- K1: masked stage + patch scores + event count + padded downsample ----------------
__global__ void __launch_bounds__(256) k_pre(const float* __restrict__ x,
    float* __restrict__ scores, float* __restrict__ P, unsigned* __restrict__ active_count) {
  const int blk = blockIdx.x, tb = blk >> 2, chunk = blk & 3;
  const int r0 = chunk * 16;           // periph rows r0..r0+15
  const int tid = threadIdx.x;
  __shared__ float xt[34*256];         // masked raw rows 2r0-1 .. 2r0+32
  __shared__ unsigned wsum[4];
  const float* img = x + (size_t)tb * 32768;
  unsigned cnt = 0;
  for (int i4 = tid; i4 < 34*64; i4 += 256) {
    const int rr = i4 >> 6, off4 = i4 & 63;
    const int xr = 2*r0 - 1 + rr;
    float4 vv = make_float4(0.f, 0.f, 0.f, 0.f);
    if (xr >= 0 && xr < H_) {
      vv = *reinterpret_cast<const float4*>(img + (size_t)xr*256 + off4*4);
      if (rr >= 1 && rr <= 32) {
        cnt += (fabsf(vv.x) > 0.5f) + (fabsf(vv.y) > 0.5f)
             + (fabsf(vv.z) > 0.5f) + (fabsf(vv.w) > 0.5f);
      }
      vv.x = (fabsf(vv.x) > 0.5f) ? vv.x : 0.f;
      vv.y = (fabsf(vv.y) > 0.5f) ? vv.y : 0.f;
      vv.z = (fabsf(vv.z) > 0.5f) ? vv.z : 0.f;
      vv.w = (fabsf(vv.w) > 0.5f) ? vv.w : 0.f;
    }
    *reinterpret_cast<float4*>(&xt[i4*4]) = vv;
  }
  unsigned c64 = cnt;
#pragma unroll
  for (int off = 32; off > 0; off >>= 1) c64 += __shfl_down(c64, off);
  if ((tid & 63) == 0) wsum[tid >> 6] = c64;
  __syncthreads();
  if (tid == 0) atomicAdd(active_count, wsum[0] + wsum[1] + wsum[2] + wsum[3]);
  // ---- patch scores: 64 patches (4 patch-rows x 16), 4 threads/patch ----
  {
    const int patch = tid >> 2, q = tid & 3;
    const int prl = patch >> 4, pc = patch & 15;
    const int row = 1 + prl*8 + q*2;
    float s = 0.f;
#pragma unroll
    for (int r2 = 0; r2 < 2; ++r2)
#pragma unroll
      for (int j = 0; j < 4; ++j) {
        const float4 vv = *reinterpret_cast<const float4*>(&xt[(row + r2)*256 + pc*16 + j*4]);
        s += fabsf(vv.x) + fabsf(vv.y) + fabsf(vv.z) + fabsf(vv.w);
      }
    s += __shfl_down(s, 1);
    s += __shfl_down(s, 2);
    if (q == 0) scores[tb*NP_ + chunk*64 + patch] = s * (1.f/128.f);
  }
  // ---- padded downsample ----
  float* Pt = P + (size_t)tb * PTB;
  if (tid < 128) {                     // zero col pads (px -2,-1,64,65) for our 16 rows
    const int r = tid >> 3, rem = tid & 7;
    const int px4 = rem >> 1, ci = rem & 1;
    const int px = (px4 < 2) ? (px4 - 2) : (62 + px4);
    Pt[(r0 + r + 1)*PROW + (px + 2)*2 + ci] = 0.f;
  }
  if (chunk == 0 && tid < PROW) Pt[tid] = 0.f;            // pad row -1
  if (chunk == 3 && tid < PROW) Pt[65*PROW + tid] = 0.f;  // pad row 64
#pragma unroll
  for (int k = 0; k < 8; ++k) {
    const int idx = k*256 + tid;       // (row16*64+col)*2+ci
    const int ci = idx & 1, rest = idx >> 1;
    const int col = rest & 63, row16 = rest >> 6;
    const int pr = r0 + row16;
    float wy0=0.125f, wy1=0.375f, wy2=0.375f, wy3=0.125f;
    if (pr == 0)       { wy0=0.f;     wy1=3.f/7.f; wy2=3.f/7.f; wy3=1.f/7.f; }
    else if (pr == 63) { wy0=1.f/7.f; wy1=3.f/7.f; wy2=3.f/7.f; wy3=0.f; }
    float wx0=0.125f, wx1=0.375f, wx2=0.375f, wx3=0.125f;
    if (col == 0)       { wx0=0.f;     wx1=3.f/7.f; wx2=3.f/7.f; wx3=1.f/7.f; }
    else if (col == 63) { wx0=1.f/7.f; wx1=3.f/7.f; wx2=3.f/7.f; wx3=0.f; }
    const int lr = 2*row16;            // xt row of tap j=0
    const int cc0 = 2*col - 1;
    float val = 0.f;
#pragma unroll
    for (int j = 0; j < 4; ++j) {
      const float wyj = (j==0)?wy0:(j==1)?wy1:(j==2)?wy2:wy3;
      float h = 0.f;
#pragma unroll
      for (int i = 0; i < 4; ++i) {
        const float wxi = (i==0)?wx0:(i==1)?wx1:(i==2)?wx2:wx3;
        int cc = cc0 + i; cc = cc < 0 ? 0 : (cc > W_-1 ? W_-1 : cc);
        h += wxi * xt[(lr + j)*256 + cc*2 + ci];
      }
      val += wyj * h;
    }
    Pt[(pr + 1)*PROW + (col + 2)*2 + ci] = val;
  }
}

// ---------------- K2: rank+argmax, fovea conv -> saliency -> channel gate ----------------
__global__ void __launch_bounds__(512) k_gate(const float* __restrict__ x,
    const float* __restrict__ scores, const float* __restrict__ wf,
    int2* __restrict__ y0x0, float* __restrict__ chan_gate,
    unsigned* __restrict__ route_count, unsigned* __restrict__ chan_count) {
  const int tb = blockIdx.x, tid = threadIdx.x;
  __shared__ float sm[NP_];
  __shared__ float tile[34*68];        // [34 rows][34 px * 2ch], zero-padded
  __shared__ float salred[512];
  __shared__ float salv[64];
  __shared__ int2 syx;
  if (tid < 256) sm[tid] = scores[tb*NP_ + tid];
  __syncthreads();
  if (tid < 256) {
    const float v = sm[tid];
    int cg = 0, eqb = 0;
    for (int q = 0; q < NP_; ++q) {
      cg  += (sm[q] > v) ? 1 : 0;
      eqb += ((sm[q] == v) && (q < tid)) ? 1 : 0;
    }
    if (cg < 4) atomicAdd(&route_count[tid], 1u);
    if (cg == 0 && eqb == 0) {
      const int cy = (tid >> 4)*8 + 4, cx = (tid & 15)*8 + 4;
      int y0 = cy - 16; y0 = y0 < 0 ? 0 : (y0 > 96 ? 96 : y0);
      int x0 = cx - 16; x0 = x0 < 0 ? 0 : (x0 > 96 ? 96 : x0);
      y0x0[tb] = make_int2(y0, x0);
      syx = make_int2(y0, x0);
    }
  }
  for (int i = tid; i < 34*68; i += 512) tile[i] = 0.f;
  __syncthreads();
  const int2 yx = syx;
  {                                    // fill interior: 32 rows x 16 segs x 2px
    const int row = tid >> 4, seg = tid & 15;
    const float* src = x + (size_t)tb*32768 + (size_t)(yx.x + row)*256 + (yx.y + seg*2)*2;
    float2 a = *reinterpret_cast<const float2*>(src);
    float2 bq = *reinterpret_cast<const float2*>(src + 2);
    a.x  = (fabsf(a.x)  > 0.5f) ? a.x  : 0.f;
    a.y  = (fabsf(a.y)  > 0.5f) ? a.y  : 0.f;
    bq.x = (fabsf(bq.x) > 0.5f) ? bq.x : 0.f;
    bq.y = (fabsf(bq.y) > 0.5f) ? bq.y : 0.f;
    float* dst = &tile[(row + 1)*68 + (seg*2 + 1)*2];
    *reinterpret_cast<float2*>(dst)     = a;
    *reinterpret_cast<float2*>(dst + 2) = bq;
  }
  __syncthreads();
  const int c = tid & 63, grp = tid >> 6, xg = grp & 3, rh = grp >> 2;
  float wreg[18];
#pragma unroll
  for (int k = 0; k < 18; ++k) wreg[k] = wf[k*CF_ + c];
  const float* tbase = &tile[(rh*16)*68 + xg*16];
  float4 wb[3][5];
#pragma unroll
  for (int m = 0; m < 5; ++m) {
    wb[0][m] = *reinterpret_cast<const float4*>(tbase + m*4);
    wb[1][m] = *reinterpret_cast<const float4*>(tbase + 68 + m*4);
  }
  float sal = 0.f;
#pragma unroll
  for (int yy = 0; yy < 16; ++yy) {
#pragma unroll
    for (int m = 0; m < 5; ++m)
      wb[(yy+2)%3][m] = *reinterpret_cast<const float4*>(tbase + (yy+2)*68 + m*4);
#pragma unroll
    for (int k = 0; k < 8; ++k) {
      float acc = 0.f;
#pragma unroll
      for (int dy = 0; dy < 3; ++dy) {
#pragma unroll
        for (int dx = 0; dx < 3; ++dx) {
          const int r = k + dx;
          const float4 f = wb[(yy+dy)%3][r >> 1];
          acc += f4c(f, (r&1)*2)     * wreg[(dy*3+dx)*2]
               + f4c(f, (r&1)*2 + 1) * wreg[(dy*3+dx)*2 + 1];
        }
      }
      sal += fabsf(acc);
    }
  }
  salred[grp*64 + c] = sal;
  __syncthreads();
  if (tid < 64) {
    float s = 0.f;
#pragma unroll
    for (int g = 0; g < 8; ++g) s += salred[g*64 + tid];
    salv[tid] = s * (1.f/1024.f);
  }
  __syncthreads();
  if (tid < 64) {
    const float sv = salv[tid];
    int cg = 0;
    for (int q = 0; q < 64; ++q) cg += (salv[q] > sv) ? 1 : 0;
    const float gate = (cg < 16) ? 1.f : 0.f;
    chan_gate[tb*CF_ + tid] = gate;
    if (gate > 0.f) atomicAdd(&chan_count[tid], 1u);
  }
}

// ---------------- K3: fused persistent membranes (fovea: blocks 0..1023, periph: 1024..3071) ----------------
__global__ void __launch_bounds__(256) k_mem(const float* __restrict__ x,
    const float* __restrict__ P, const float* __restrict__ wf, const float* __restrict__ wp,
    const int2* __restrict__ y0x0, const float* __restrict__ chan_gate,
    unsigned* __restrict__ sf_cnt, unsigned* __restrict__ sp_cnt) {
  const int tid = threadIdx.x;
  if (blockIdx.x < 1024) {
    const int blk = blockIdx.x, b = blk >> 5, row = blk & 31;
    const int c = tid & 63, xg = tid >> 6, px0 = xg*8;
    float wreg[18];
#pragma unroll
    for (int k = 0; k < 18; ++k) wreg[k] = wf[k*CF_ + c];
    float v[8];
#pragma unroll
    for (int i = 0; i < 8; ++i) v[i] = 0.f;
    for (int t = 0; t < T_; ++t) {
      const int tb = t*B_ + b;
      const int2 yx = y0x0[tb];
      const float gate = chan_gate[tb*CF_ + c];
      float2 win[3][10];
#pragma unroll
      for (int rr = 0; rr < 3; ++rr) {
        const int wr = row - 1 + rr;
        const bool rowok = (wr >= 0 && wr < 32);
        const int wrc = rowok ? wr : 0;
        const float* base = x + (size_t)tb*32768 + (size_t)(yx.x + wrc)*256 + yx.y*2;
#pragma unroll
        for (int j = 0; j < 10; ++j) {
          const int px = px0 - 1 + j;
          const int pxc = (px < 0) ? 0 : (px > 31 ? 31 : px);
          const float2 raw = *reinterpret_cast<const float2*>(base + pxc*2);
          const bool ok = rowok && (px >= 0) && (px < 32);
          win[rr][j].x = (ok && fabsf(raw.x) > 0.5f) ? raw.x : 0.f;
          win[rr][j].y = (ok && fabsf(raw.y) > 0.5f) ? raw.y : 0.f;
        }
      }
      unsigned cnt = 0;
#pragma unroll
      for (int k = 0; k < 8; ++k) {
        float acc = 0.f;
#pragma unroll
        for (int dy = 0; dy < 3; ++dy)
#pragma unroll
          for (int dx = 0; dx < 3; ++dx) {
            const float2 f = win[dy][k + dx];
            acc += f.x*wreg[(dy*3+dx)*2] + f.y*wreg[(dy*3+dx)*2 + 1];
          }
        float nv = 0.9f*v[k] + acc*gate;
        if (nv > 1.0f) { nv -= 1.0f; ++cnt; }
        v[k] = nv;
      }
      atomicAdd(&sf_cnt[tb*CF_ + c], cnt);
    }
  } else {
    const int blk = blockIdx.x - 1024, b = blk >> 6, row = blk & 63;
    const int c = tid & 31, xg = tid >> 5, px0 = xg*8;
    float wreg[18];
#pragma unroll
    for (int k = 0; k < 18; ++k) wreg[k] = wp[k*CP_ + c];
    float v[8];
#pragma unroll
    for (int i = 0; i < 8; ++i) v[i] = 0.f;
    for (int t = 0; t < T_; ++t) {
      const int tb = t*B_ + b;
      const float* base = P + (size_t)tb*PTB + (size_t)row*PROW + px0*2;
      float4 win[3][6];
#pragma unroll
      for (int rr = 0; rr < 3; ++rr)
#pragma unroll
        for (int m = 0; m < 6; ++m)
          win[rr][m] = *reinterpret_cast<const float4*>(base + rr*PROW + m*4);
      unsigned cnt = 0;
#pragma unroll
      for (int k = 0; k < 8; ++k) {
        float acc = 0.f;
#pragma unroll
        for (int dy = 0; dy < 3; ++dy)
#pragma unroll
          for (int dx = 0; dx < 3; ++dx) {
            const int r = k + dx + 1;
            const float4 f = win[dy][r >> 1];
            acc += f4c(f, (r&1)*2)     * wreg[(dy*3+dx)*2]
                 + f4c(f, (r&1)*2 + 1) * wreg[(dy*3+dx)*2 + 1];
          }
        float nv = 0.9f*v[k] + acc;
        if (nv > 1.0f) { nv -= 1.0f; ++cnt; }
        v[k] = nv;
      }
      cnt += __shfl_down(cnt, 32);
      if ((tid & 63) < 32) atomicAdd(&sp_cnt[tb*CP_ + c], cnt);
    }
  }
}

// ---------------- K4: logits ----------------
__global__ void __launch_bounds__(128) k_logits(const float* __restrict__ scores,
    const unsigned* __restrict__ sf_cnt, const unsigned* __restrict__ sp_cnt,
    const float* __restrict__ head_w, const float* __restrict__ head_b,
    const float* __restrict__ route_w, const float* __restrict__ route_b,
    float* __restrict__ logits) {
  const int tb = blockIdx.x, o = threadIdx.x;
  __shared__ float sc[NP_];
  __shared__ float fu[96];
  sc[o]       = scores[tb*NP_ + o];
  sc[o + 128] = scores[tb*NP_ + o + 128];
  if (o < 64)       fu[o] = (float)sf_cnt[tb*CF_ + o] * (1.f/1024.f);
  else if (o < 96)  fu[o] = (float)sp_cnt[tb*CP_ + (o - 64)] * (1.f/4096.f);
  __syncthreads();
  float acc = head_b[o] + route_b[o];
#pragma unroll 8
  for (int k = 0; k < 96; ++k)  acc += fu[k]*head_w[k*OUT_ + o];
#pragma unroll 8
  for (int p = 0; p < NP_; ++p) acc += sc[p]*route_w[p*OUT_ + o];
  logits[tb*OUT_ + o] = acc;
}

// ---------------- K5: finalize ----------------
__global__ void __launch_bounds__(256) k_final(const float* __restrict__ logits,
    float* __restrict__ dout, const unsigned* __restrict__ sf_cnt,
    const unsigned* __restrict__ sp_cnt, const unsigned* __restrict__ cnts) {
  const int blk = blockIdx.x, tid = threadIdx.x;
  if (blk < 16) {
    const int idx = blk*256 + tid;
    const int b = idx >> 7, o = idx & 127;
    float s = 0.f;
#pragma unroll
    for (int t = 0; t < T_; ++t) s += logits[(t*B_ + b)*OUT_ + o];
    dout[idx] = s * (1.f/32.f);
  } else {
    unsigned sfs = 0, sps = 0;
    for (int i = tid; i < T_*B_*CF_; i += 256) sfs += sf_cnt[i];
    for (int i = tid; i < T_*B_*CP_; i += 256) sps += sp_cnt[i];
    __shared__ unsigned r1[256], r2[256];
    r1[tid] = sfs; r2[tid] = sps;
    __syncthreads();
    for (int off = 128; off > 0; off >>= 1) {
      if (tid < off) { r1[tid] += r1[tid + off]; r2[tid] += r2[tid + off]; }
      __syncthreads();
    }
    if (tid == 0) {
      dout[OFF_SR]     = (float)r1[0] * (1.f/67108864.f);
      dout[OFF_SR + 1] = (float)r2[0] * (1.f/134217728.f);
      dout[OFF_ACTIVE] = (float)cnts[0] * (1.f/33554432.f);
    }
    dout[OFF_ROUTE + tid] = (float)cnts[1 + tid] * (1.f/1024.f);
    if (tid < 64) dout[OFF_CHAN + tid] = (float)cnts[257 + tid] * (1.f/1024.f);
  }
}

extern "C" void kernel_launch(void* const* d_in, const int* in_sizes, int n_in,
                              void* d_out, int out_size, void* d_ws, size_t ws_size,
                              hipStream_t stream) {
  const float* x       = (const float*)d_in[0];
  const float* wf      = (const float*)d_in[1];
  const float* wp      = (const float*)d_in[2];
  const float* head_w  = (const float*)d_in[3];
  const float* head_b  = (const float*)d_in[4];
  const float* route_w = (const float*)d_in[5];
  const float* route_b = (const float*)d_in[6];
  float* out = (float*)d_out;

  float*    ws_P      = (float*)d_ws;                       // 1024*8976 floats (padded)
  float*    ws_scores = ws_P + (size_t)1024*PTB;            // T*B*256
  float*    ws_gate   = ws_scores + T_*B_*NP_;              // T*B*64
  int2*     ws_yx     = (int2*)(ws_gate + T_*B_*CF_);       // T*B
  unsigned* ws_sf     = (unsigned*)(ws_yx + T_*B_);         // T*B*64
  unsigned* ws_sp     = ws_sf + T_*B_*CF_;                  // T*B*32
  unsigned* ws_cnt    = ws_sp + T_*B_*CP_;                  // 1 + 256 + 64

  hipMemsetAsync(ws_sf, 0, (size_t)(T_*B_*CF_ + T_*B_*CP_ + 321)*sizeof(unsigned), stream);

  k_pre   <<<T_*B_*4, 256, 0, stream>>>(x, ws_scores, ws_P, ws_cnt);
  k_gate  <<<T_*B_,   512, 0, stream>>>(x, ws_scores, wf, ws_yx, ws_gate,
                                        ws_cnt + 1, ws_cnt + 257);
  k_mem   <<<3072,    256, 0, stream>>>(x, ws_P, wf, wp, ws_yx, ws_gate, ws_sf, ws_sp);
  k_logits<<<T_*B_,   128, 0, stream>>>(ws_scores, ws_sf, ws_sp, head_w, head_b,
                                        route_w, route_b, out + OFF_LOGITS);
  k_final <<<17, 256, 0, stream>>>(out + OFF_LOGITS, out, ws_sf, ws_sp, ws_cnt);
}